// Round 16
// baseline (183.746 us; speedup 1.0000x reference)
//
#include <hip/hip_runtime.h>
#include <hip/hip_bf16.h>
#include <stdint.h>

#define B_ROWS 2048
#define SEQ 512
#define VOC 30000
#define DMODEL 768
#define K1 1.2f
#define BPAR 0.75f
#define NT 192    // gather: 3 waves; lane=tid%96 owns a ushort8 (16B) chunk, half=tid/96
#define PF 4      // prefetch batches of 4 x 16B = 16 load-dwords (R7-proven budget)
#define TGX 235   // ceil(VOC/128) transpose tiles in t
#define TGY 12    // DMODEL/64 transpose tiles in j

// ---------------- Kernel 1: fused doc-prep + W-transpose -------------------------------
// Identical to R15 except tokens premultiplied by DMODEL/8 = 96 (ushort8-row offset).
__launch_bounds__(256)
__global__ void prep_trans(const float* __restrict__ W, __hip_bfloat16* __restrict__ Wb,
                           const int* __restrict__ ids, const int* __restrict__ mask,
                           int* __restrict__ stoks_g, float* __restrict__ wts_g,
                           int* __restrict__ n_g) {
    __shared__ ushort smem[64 * 130];   // 16,640 B
    int bid = blockIdx.x;
    int tid = threadIdx.x;

    if (bid < B_ROWS) {
        // ---- doc-prep role ----
        int b = bid;
        int*   stoks = (int*)smem;                    // 512 ints  (2048 B)
        float* wts   = (float*)((char*)smem + 2048);  // 512 f32   (2048 B)
        int*   nvp   = (int*)((char*)smem + 4096);

        if (tid == 0) *nvp = 0;
        __syncthreads();

        for (int i = tid; i < SEQ; i += 256) {
            int id = ids[(size_t)b * SEQ + i];
            int m  = mask[(size_t)b * SEQ + i];
            if (m == 1 && id > 100 && id < VOC) {
                stoks[atomicAdd(nvp, 1)] = id;
            }
        }
        __syncthreads();
        int n = *nvp;   // == doc_len (positions with multiplicity)

        for (int i = n + tid; i < SEQ; i += 256) stoks[i] = 0x7fffffff;

        for (int k = 2; k <= SEQ; k <<= 1) {
            for (int j = k >> 1; j > 0; j >>= 1) {
                __syncthreads();
                for (int i = tid; i < SEQ; i += 256) {
                    int ixj = i ^ j;
                    if (ixj > i) {
                        int a = stoks[i], c = stoks[ixj];
                        if ((a > c) == ((i & k) == 0)) { stoks[i] = c; stoks[ixj] = a; }
                    }
                }
            }
        }
        __syncthreads();

        float kln = K1 * fmaxf(1.0f + BPAR * ((float)n / 100.0f - 1.0f), 0.5f);
        for (int i = tid; i < n; i += 256) {
            int t = stoks[i];
            int lo = i; while (lo > 0 && stoks[lo - 1] == t) lo--;
            int hi = i; while (hi < n - 1 && stoks[hi + 1] == t) hi++;
            wts[i] = (K1 + 1.0f) / ((float)(hi - lo + 1) + kln);
        }
        __syncthreads();

        for (int i = tid; i < n; i += 256) {
            stoks_g[(size_t)b * SEQ + i] = stoks[i] * (DMODEL / 8);  // ushort8-row offset
            wts_g[(size_t)b * SEQ + i]   = wts[i];
        }
        if (tid == 0) n_g[b] = n;
    } else {
        // ---- transpose role ----
        ushort (*tile)[130] = (ushort(*)[130])smem;   // [j_local][t_local]
        int tb = bid - B_ROWS;
        int bx = tb % TGX, by = tb / TGX;
        int tBase = bx * 128;
        int jBase = by * 64;
        int tx = tid & 63;    // lane
        int ty = tid >> 6;    // wave

#pragma unroll
        for (int jj = 0; jj < 16; jj++) {
            int j = jBase + jj * 4 + ty;
            int t = tBase + tx * 2;
            if (t < VOC) {   // VOC even -> full float2 in range
                float2 v = *(const float2*)(W + (size_t)j * VOC + t);
                ushort2 u;
                u.x = __bfloat16_as_ushort(__float2bfloat16(v.x));
                u.y = __bfloat16_as_ushort(__float2bfloat16(v.y));
                *(ushort2*)&tile[jj * 4 + ty][tx * 2] = u;
            }
        }
        __syncthreads();

#pragma unroll
        for (int i = 0; i < 32; i++) {
            int trow = i * 4 + ty;
            int t = tBase + trow;
            if (t < VOC) {
                ((ushort*)Wb)[(size_t)t * DMODEL + jBase + tx] = tile[tx][trow];
            }
        }
    }
}

__device__ __forceinline__ float bl(uint32_t d) {   // low bf16 of dword -> f32
    union { uint32_t u; float f; } v; v.u = d << 16; return v.f;
}
__device__ __forceinline__ float bh(uint32_t d) {   // high bf16 of dword -> f32
    union { uint32_t u; float f; } v; v.u = d & 0xffff0000u; return v.f;
}

// ---------------- Kernel 2: pure gather + normalize ------------------------------------
// 2 tokens/iteration: lane = tid%96 owns ushort8 chunk (16B dwordx4 load), half = tid/96
// picks token p+half. Per 2 tokens/thread: 1 VMEM + 2 LDS + 1 addr + 8 unpack + 8 FMA
// (was 2 VMEM + 4 LDS + 2 addr). PF=4 keeps the proven 16 load-dword budget while
// covering 8 tokens/batch. Halves stay within 1 token -> sweep phase-lock preserved.
__launch_bounds__(NT, 6)
__global__ void bm25_gather(const int* __restrict__ stoks_g, const float* __restrict__ wts_g,
                            const int* __restrict__ n_g,
                            const __hip_bfloat16* __restrict__ Wb,
                            float* __restrict__ out) {
    __shared__ int   stoks[SEQ];
    __shared__ float wts[SEQ];
    __shared__ float accred[DMODEL];   // half-1 partials, then combined row
    __shared__ float wred[3];

    int b = blockIdx.x;
    int tid = threadIdx.x;
    int lane = tid % 96;
    int half = tid / 96;
    int n = n_g[b];   // block-uniform

    for (int i = tid; i < n; i += NT) {
        stoks[i] = stoks_g[(size_t)b * SEQ + i];
        wts[i]   = wts_g[(size_t)b * SEQ + i];
    }
    __syncthreads();

    const char* __restrict__ Wbase = (const char*)Wb;
    float acc[8] = {0.f, 0.f, 0.f, 0.f, 0.f, 0.f, 0.f, 0.f};
    int p = 0;
    int npair = n & ~1;

    for (; p + 2 * PF <= npair; p += 2 * PF) {
        uint4 r[PF]; float w[PF];
#pragma unroll
        for (int q = 0; q < PF; q++) {
            int pp = p + q * 2 + half;
            r[q] = *(const uint4*)(Wbase + ((size_t)stoks[pp] + lane) * 16);
            w[q] = wts[pp];
        }
#pragma unroll
        for (int q = 0; q < PF; q++) {
            acc[0] = fmaf(w[q], bl(r[q].x), acc[0]);
            acc[1] = fmaf(w[q], bh(r[q].x), acc[1]);
            acc[2] = fmaf(w[q], bl(r[q].y), acc[2]);
            acc[3] = fmaf(w[q], bh(r[q].y), acc[3]);
            acc[4] = fmaf(w[q], bl(r[q].z), acc[4]);
            acc[5] = fmaf(w[q], bh(r[q].z), acc[5]);
            acc[6] = fmaf(w[q], bl(r[q].w), acc[6]);
            acc[7] = fmaf(w[q], bh(r[q].w), acc[7]);
        }
    }
    // pair tail (npair - p is 0,2,4, or 6) plus odd token: half 0 handles them alone
    if (half == 0) {
        for (; p < n; p++) {
            float w = wts[p];
            uint4 r = *(const uint4*)(Wbase + ((size_t)stoks[p] + lane) * 16);
            acc[0] = fmaf(w, bl(r.x), acc[0]);
            acc[1] = fmaf(w, bh(r.x), acc[1]);
            acc[2] = fmaf(w, bl(r.y), acc[2]);
            acc[3] = fmaf(w, bh(r.y), acc[3]);
            acc[4] = fmaf(w, bl(r.z), acc[4]);
            acc[5] = fmaf(w, bh(r.z), acc[5]);
            acc[6] = fmaf(w, bl(r.w), acc[6]);
            acc[7] = fmaf(w, bh(r.w), acc[7]);
        }
    }

    // combine halves: half-1 stages partials, half-0 adds, writes combined row to LDS
    if (half == 1) {
#pragma unroll
        for (int d = 0; d < 8; d++) accred[lane * 8 + d] = acc[d];
    }
    __syncthreads();
    if (half == 0) {
#pragma unroll
        for (int d = 0; d < 8; d++) accred[lane * 8 + d] += acc[d];
    }
    __syncthreads();

    // proven norm + store path: thread owns float4 chunk `tid` of the combined row
    float4 a4 = ((const float4*)accred)[tid];
    float ss = a4.x * a4.x + a4.y * a4.y + a4.z * a4.z + a4.w * a4.w;
#pragma unroll
    for (int off = 32; off > 0; off >>= 1) ss += __shfl_down(ss, off);
    if ((tid & 63) == 0) wred[tid >> 6] = ss;
    __syncthreads();
    float inv = rsqrtf(fmaxf(wred[0] + wred[1] + wred[2], 1e-30f));

    float4 o;
    o.x = a4.x * inv; o.y = a4.y * inv; o.z = a4.z * inv; o.w = a4.w * inv;
    ((float4*)(out + (size_t)b * DMODEL))[tid] = o;
}

extern "C" void kernel_launch(void* const* d_in, const int* in_sizes, int n_in,
                              void* d_out, int out_size, void* d_ws, size_t ws_size,
                              hipStream_t stream) {
    const int*   ids  = (const int*)d_in[0];
    const int*   mask = (const int*)d_in[1];
    const float* W    = (const float*)d_in[2];
    float* out = (float*)d_out;

    char* ws = (char*)d_ws;
    __hip_bfloat16* Wb = (__hip_bfloat16*)ws;               // 46,080,000 B
    size_t off = (size_t)VOC * DMODEL * sizeof(__hip_bfloat16);
    int*   stoks_g = (int*)(ws + off);        off += (size_t)B_ROWS * SEQ * 4;  // 4 MB
    float* wts_g   = (float*)(ws + off);      off += (size_t)B_ROWS * SEQ * 4;  // 4 MB
    int*   n_g     = (int*)(ws + off);

    prep_trans<<<B_ROWS + TGX * TGY, 256, 0, stream>>>(W, Wb, ids, mask,
                                                       stoks_g, wts_g, n_g);

    bm25_gather<<<B_ROWS, NT, 0, stream>>>(stoks_g, wts_g, n_g, Wb, out);
}

// Round 17
// 148.749 us; speedup vs baseline: 1.2353x; 1.2353x over previous
//
#include <hip/hip_runtime.h>
#include <hip/hip_bf16.h>
#include <stdint.h>

#define B_ROWS 2048
#define SEQ 512
#define VOC 30000
#define DMODEL 768
#define K1 1.2f
#define BPAR 0.75f
#define NT 192    // gather: 3 waves; each thread owns one ushort4 (4 bf16) chunk
#define PF 8      // prefetch depth — R7/R13/R14/R15-proven operating point
#define TGX 235   // ceil(VOC/128) transpose tiles in t
#define TGY 12    // DMODEL/64 transpose tiles in j
#define TTILES (TGX * TGY)   // 2820

// ---------------- Kernel 1: fused W-transpose + doc-prep -------------------------------
// Blocks [0, TTILES): transpose W -> Wb bf16 (64j x 128t tiles; float2 512B reads,
//   full-128B-line writes, stride-130 LDS). Dispatched FIRST: tiles are short-lived and
//   retire continuously, so prep blocks stream in behind them and their barrier-bound
//   VALU sort overlaps the transpose's memory phase (R15 had prep first -> two
//   serialized monophases, 12us VALU-only + 24us BW-only).
// Blocks [TTILES, TTILES+B_ROWS): per-doc compact + bitonic sort + BM25 weights,
//   tokens premultiplied by DMODEL/4 (ushort4-row offset) — R15-proven logic.
__launch_bounds__(256)
__global__ void prep_trans(const float* __restrict__ W, __hip_bfloat16* __restrict__ Wb,
                           const int* __restrict__ ids, const int* __restrict__ mask,
                           int* __restrict__ stoks_g, float* __restrict__ wts_g,
                           int* __restrict__ n_g) {
    __shared__ ushort smem[64 * 130];   // 16,640 B
    int bid = blockIdx.x;
    int tid = threadIdx.x;

    if (bid < TTILES) {
        // ---- transpose role ----
        ushort (*tile)[130] = (ushort(*)[130])smem;   // [j_local][t_local]
        int bx = bid % TGX, by = bid / TGX;
        int tBase = bx * 128;
        int jBase = by * 64;
        int tx = tid & 63;    // lane
        int ty = tid >> 6;    // wave

#pragma unroll
        for (int jj = 0; jj < 16; jj++) {
            int j = jBase + jj * 4 + ty;
            int t = tBase + tx * 2;
            if (t < VOC) {   // VOC even -> full float2 in range
                float2 v = *(const float2*)(W + (size_t)j * VOC + t);
                ushort2 u;
                u.x = __bfloat16_as_ushort(__float2bfloat16(v.x));
                u.y = __bfloat16_as_ushort(__float2bfloat16(v.y));
                *(ushort2*)&tile[jj * 4 + ty][tx * 2] = u;
            }
        }
        __syncthreads();

#pragma unroll
        for (int i = 0; i < 32; i++) {
            int trow = i * 4 + ty;
            int t = tBase + trow;
            if (t < VOC) {
                ((ushort*)Wb)[(size_t)t * DMODEL + jBase + tx] = tile[tx][trow];
            }
        }
    } else {
        // ---- doc-prep role ----
        int b = bid - TTILES;
        int*   stoks = (int*)smem;                    // 512 ints  (2048 B)
        float* wts   = (float*)((char*)smem + 2048);  // 512 f32   (2048 B)
        int*   nvp   = (int*)((char*)smem + 4096);

        if (tid == 0) *nvp = 0;
        __syncthreads();

        for (int i = tid; i < SEQ; i += 256) {
            int id = ids[(size_t)b * SEQ + i];
            int m  = mask[(size_t)b * SEQ + i];
            if (m == 1 && id > 100 && id < VOC) {
                stoks[atomicAdd(nvp, 1)] = id;
            }
        }
        __syncthreads();
        int n = *nvp;   // == doc_len (positions with multiplicity)

        for (int i = n + tid; i < SEQ; i += 256) stoks[i] = 0x7fffffff;

        for (int k = 2; k <= SEQ; k <<= 1) {
            for (int j = k >> 1; j > 0; j >>= 1) {
                __syncthreads();
                for (int i = tid; i < SEQ; i += 256) {
                    int ixj = i ^ j;
                    if (ixj > i) {
                        int a = stoks[i], c = stoks[ixj];
                        if ((a > c) == ((i & k) == 0)) { stoks[i] = c; stoks[ixj] = a; }
                    }
                }
            }
        }
        __syncthreads();

        float kln = K1 * fmaxf(1.0f + BPAR * ((float)n / 100.0f - 1.0f), 0.5f);
        for (int i = tid; i < n; i += 256) {
            int t = stoks[i];
            int lo = i; while (lo > 0 && stoks[lo - 1] == t) lo--;
            int hi = i; while (hi < n - 1 && stoks[hi + 1] == t) hi++;
            wts[i] = (K1 + 1.0f) / ((float)(hi - lo + 1) + kln);
        }
        __syncthreads();

        for (int i = tid; i < n; i += 256) {
            stoks_g[(size_t)b * SEQ + i] = stoks[i] * (DMODEL / 4);  // ushort4-row offset
            wts_g[(size_t)b * SEQ + i]   = wts[i];
        }
        if (tid == 0) n_g[b] = n;
    }
}

__device__ __forceinline__ float b2f(unsigned short h) {
    union { uint32_t u; float f; } v; v.u = ((uint32_t)h) << 16; return v.f;
}

// ---------------- Kernel 2: pure gather + normalize ------------------------------------
// BYTE-IDENTICAL to R13/R14/R15's bm25_gather (107 us, FETCH 326 MB — proven 4x).
__launch_bounds__(NT, 6)
__global__ void bm25_gather(const int* __restrict__ stoks_g, const float* __restrict__ wts_g,
                            const int* __restrict__ n_g,
                            const __hip_bfloat16* __restrict__ Wb,
                            float* __restrict__ out) {
    __shared__ int   stoks[SEQ];
    __shared__ float wts[SEQ];
    __shared__ float wred[3];

    int b = blockIdx.x;
    int tid = threadIdx.x;
    int n = n_g[b];   // block-uniform

    for (int i = tid; i < n; i += NT) {
        stoks[i] = stoks_g[(size_t)b * SEQ + i];
        wts[i]   = wts_g[(size_t)b * SEQ + i];
    }
    __syncthreads();

    // gather-accumulate in ascending vocab order; thread owns bf16x4 chunk `tid`
    const ushort4* __restrict__ Wb4 = (const ushort4*)Wb;
    float4 acc = make_float4(0.f, 0.f, 0.f, 0.f);
    int p = 0;
    for (; p + PF <= n; p += PF) {
        ushort4 r[PF];
        float   w[PF];
#pragma unroll
        for (int q = 0; q < PF; q++) {
            r[q] = Wb4[(size_t)stoks[p + q] + tid];
            w[q] = wts[p + q];
        }
#pragma unroll
        for (int q = 0; q < PF; q++) {
            acc.x = fmaf(w[q], b2f(r[q].x), acc.x);
            acc.y = fmaf(w[q], b2f(r[q].y), acc.y);
            acc.z = fmaf(w[q], b2f(r[q].z), acc.z);
            acc.w = fmaf(w[q], b2f(r[q].w), acc.w);
        }
    }
    for (; p < n; p++) {
        float w = wts[p];
        ushort4 r = Wb4[(size_t)stoks[p] + tid];
        acc.x = fmaf(w, b2f(r.x), acc.x);
        acc.y = fmaf(w, b2f(r.y), acc.y);
        acc.z = fmaf(w, b2f(r.z), acc.z);
        acc.w = fmaf(w, b2f(r.w), acc.w);
    }

    // L2 norm over 768 dims (intermediate normalize cancels; 1e-10 term ~1e-10 rel)
    float ss = acc.x * acc.x + acc.y * acc.y + acc.z * acc.z + acc.w * acc.w;
#pragma unroll
    for (int off = 32; off > 0; off >>= 1) ss += __shfl_down(ss, off);
    if ((tid & 63) == 0) wred[tid >> 6] = ss;
    __syncthreads();
    float inv = rsqrtf(fmaxf(wred[0] + wred[1] + wred[2], 1e-30f));

    float4 o;
    o.x = acc.x * inv; o.y = acc.y * inv; o.z = acc.z * inv; o.w = acc.w * inv;
    ((float4*)(out + (size_t)b * DMODEL))[tid] = o;
}

extern "C" void kernel_launch(void* const* d_in, const int* in_sizes, int n_in,
                              void* d_out, int out_size, void* d_ws, size_t ws_size,
                              hipStream_t stream) {
    const int*   ids  = (const int*)d_in[0];
    const int*   mask = (const int*)d_in[1];
    const float* W    = (const float*)d_in[2];
    float* out = (float*)d_out;

    char* ws = (char*)d_ws;
    __hip_bfloat16* Wb = (__hip_bfloat16*)ws;               // 46,080,000 B
    size_t off = (size_t)VOC * DMODEL * sizeof(__hip_bfloat16);
    int*   stoks_g = (int*)(ws + off);        off += (size_t)B_ROWS * SEQ * 4;  // 4 MB
    float* wts_g   = (float*)(ws + off);      off += (size_t)B_ROWS * SEQ * 4;  // 4 MB
    int*   n_g     = (int*)(ws + off);

    prep_trans<<<TTILES + B_ROWS, 256, 0, stream>>>(W, Wb, ids, mask,
                                                    stoks_g, wts_g, n_g);

    bm25_gather<<<B_ROWS, NT, 0, stream>>>(stoks_g, wts_g, n_g, Wb, out);
}

// Round 18
// 144.525 us; speedup vs baseline: 1.2714x; 1.0292x over previous
//
#include <hip/hip_runtime.h>
#include <hip/hip_bf16.h>
#include <stdint.h>

#define B_ROWS 2048
#define SEQ 512
#define VOC 30000
#define DMODEL 768
#define K1 1.2f
#define BPAR 0.75f
#define NT 192    // gather: 3 waves; each thread owns one ushort4 (4 bf16) chunk
#define PF 8      // prefetch depth — R7/R13/R14/R15/R17-proven operating point
#define TGX 235   // ceil(VOC/128) transpose tiles in t
#define TGY 12    // DMODEL/64 transpose tiles in j
#define TTILES (TGX * TGY)           // 2820
#define NBLK (TTILES + B_ROWS)       // 4868

// ---------------- Kernel 1: fused W-transpose + doc-prep, INTERLEAVED roles ------------
// R15 (prep-first) and R17 (transpose-first) both serialized into monophases
// (VALU-only sort with HBM idle / BW-only transpose with VALU idle). Proportional
// interleave via the floor bijection keeps every CU holding a mix of both block types
// from t=0 -> the barrier-bound sort hides under the transpose's memory phase.
// Roles byte-identical to R15/R17; only the bid->role map changed.
__launch_bounds__(256)
__global__ void prep_trans(const float* __restrict__ W, __hip_bfloat16* __restrict__ Wb,
                           const int* __restrict__ ids, const int* __restrict__ mask,
                           int* __restrict__ stoks_g, float* __restrict__ wts_g,
                           int* __restrict__ n_g) {
    __shared__ ushort smem[64 * 130];   // 16,640 B
    uint32_t bid = blockIdx.x;
    int tid = threadIdx.x;

    // proportional interleave: prep iff floor((bid+1)*P/N) > floor(bid*P/N)
    uint32_t a  = bid * (uint32_t)B_ROWS / (uint32_t)NBLK;
    uint32_t b2 = (bid + 1u) * (uint32_t)B_ROWS / (uint32_t)NBLK;

    if (b2 == a) {
        // ---- transpose role (index = bid - a) ----
        ushort (*tile)[130] = (ushort(*)[130])smem;   // [j_local][t_local]
        int tb = (int)(bid - a);
        int bx = tb % TGX, by = tb / TGX;
        int tBase = bx * 128;
        int jBase = by * 64;
        int tx = tid & 63;    // lane
        int ty = tid >> 6;    // wave

#pragma unroll
        for (int jj = 0; jj < 16; jj++) {
            int j = jBase + jj * 4 + ty;
            int t = tBase + tx * 2;
            if (t < VOC) {   // VOC even -> full float2 in range
                float2 v = *(const float2*)(W + (size_t)j * VOC + t);
                ushort2 u;
                u.x = __bfloat16_as_ushort(__float2bfloat16(v.x));
                u.y = __bfloat16_as_ushort(__float2bfloat16(v.y));
                *(ushort2*)&tile[jj * 4 + ty][tx * 2] = u;
            }
        }
        __syncthreads();

#pragma unroll
        for (int i = 0; i < 32; i++) {
            int trow = i * 4 + ty;
            int t = tBase + trow;
            if (t < VOC) {
                ((ushort*)Wb)[(size_t)t * DMODEL + jBase + tx] = tile[tx][trow];
            }
        }
    } else {
        // ---- doc-prep role (index = a) ----
        int b = (int)a;
        int*   stoks = (int*)smem;                    // 512 ints  (2048 B)
        float* wts   = (float*)((char*)smem + 2048);  // 512 f32   (2048 B)
        int*   nvp   = (int*)((char*)smem + 4096);

        if (tid == 0) *nvp = 0;
        __syncthreads();

        for (int i = tid; i < SEQ; i += 256) {
            int id = ids[(size_t)b * SEQ + i];
            int m  = mask[(size_t)b * SEQ + i];
            if (m == 1 && id > 100 && id < VOC) {
                stoks[atomicAdd(nvp, 1)] = id;
            }
        }
        __syncthreads();
        int n = *nvp;   // == doc_len (positions with multiplicity)

        for (int i = n + tid; i < SEQ; i += 256) stoks[i] = 0x7fffffff;

        for (int k = 2; k <= SEQ; k <<= 1) {
            for (int j = k >> 1; j > 0; j >>= 1) {
                __syncthreads();
                for (int i = tid; i < SEQ; i += 256) {
                    int ixj = i ^ j;
                    if (ixj > i) {
                        int va = stoks[i], vc = stoks[ixj];
                        if ((va > vc) == ((i & k) == 0)) { stoks[i] = vc; stoks[ixj] = va; }
                    }
                }
            }
        }
        __syncthreads();

        float kln = K1 * fmaxf(1.0f + BPAR * ((float)n / 100.0f - 1.0f), 0.5f);
        for (int i = tid; i < n; i += 256) {
            int t = stoks[i];
            int lo = i; while (lo > 0 && stoks[lo - 1] == t) lo--;
            int hi = i; while (hi < n - 1 && stoks[hi + 1] == t) hi++;
            wts[i] = (K1 + 1.0f) / ((float)(hi - lo + 1) + kln);
        }
        __syncthreads();

        for (int i = tid; i < n; i += 256) {
            stoks_g[(size_t)b * SEQ + i] = stoks[i] * (DMODEL / 4);  // ushort4-row offset
            wts_g[(size_t)b * SEQ + i]   = wts[i];
        }
        if (tid == 0) n_g[b] = n;
    }
}

__device__ __forceinline__ float b2f(unsigned short h) {
    union { uint32_t u; float f; } v; v.u = ((uint32_t)h) << 16; return v.f;
}

// ---------------- Kernel 2: pure gather + normalize ------------------------------------
// BYTE-IDENTICAL to R13/R14/R15/R17's bm25_gather (107 us, FETCH 326 MB — proven 5x).
__launch_bounds__(NT, 6)
__global__ void bm25_gather(const int* __restrict__ stoks_g, const float* __restrict__ wts_g,
                            const int* __restrict__ n_g,
                            const __hip_bfloat16* __restrict__ Wb,
                            float* __restrict__ out) {
    __shared__ int   stoks[SEQ];
    __shared__ float wts[SEQ];
    __shared__ float wred[3];

    int b = blockIdx.x;
    int tid = threadIdx.x;
    int n = n_g[b];   // block-uniform

    for (int i = tid; i < n; i += NT) {
        stoks[i] = stoks_g[(size_t)b * SEQ + i];
        wts[i]   = wts_g[(size_t)b * SEQ + i];
    }
    __syncthreads();

    // gather-accumulate in ascending vocab order; thread owns bf16x4 chunk `tid`
    const ushort4* __restrict__ Wb4 = (const ushort4*)Wb;
    float4 acc = make_float4(0.f, 0.f, 0.f, 0.f);
    int p = 0;
    for (; p + PF <= n; p += PF) {
        ushort4 r[PF];
        float   w[PF];
#pragma unroll
        for (int q = 0; q < PF; q++) {
            r[q] = Wb4[(size_t)stoks[p + q] + tid];
            w[q] = wts[p + q];
        }
#pragma unroll
        for (int q = 0; q < PF; q++) {
            acc.x = fmaf(w[q], b2f(r[q].x), acc.x);
            acc.y = fmaf(w[q], b2f(r[q].y), acc.y);
            acc.z = fmaf(w[q], b2f(r[q].z), acc.z);
            acc.w = fmaf(w[q], b2f(r[q].w), acc.w);
        }
    }
    for (; p < n; p++) {
        float w = wts[p];
        ushort4 r = Wb4[(size_t)stoks[p] + tid];
        acc.x = fmaf(w, b2f(r.x), acc.x);
        acc.y = fmaf(w, b2f(r.y), acc.y);
        acc.z = fmaf(w, b2f(r.z), acc.z);
        acc.w = fmaf(w, b2f(r.w), acc.w);
    }

    // L2 norm over 768 dims (intermediate normalize cancels; 1e-10 term ~1e-10 rel)
    float ss = acc.x * acc.x + acc.y * acc.y + acc.z * acc.z + acc.w * acc.w;
#pragma unroll
    for (int off = 32; off > 0; off >>= 1) ss += __shfl_down(ss, off);
    if ((tid & 63) == 0) wred[tid >> 6] = ss;
    __syncthreads();
    float inv = rsqrtf(fmaxf(wred[0] + wred[1] + wred[2], 1e-30f));

    float4 o;
    o.x = acc.x * inv; o.y = acc.y * inv; o.z = acc.z * inv; o.w = acc.w * inv;
    ((float4*)(out + (size_t)b * DMODEL))[tid] = o;
}

extern "C" void kernel_launch(void* const* d_in, const int* in_sizes, int n_in,
                              void* d_out, int out_size, void* d_ws, size_t ws_size,
                              hipStream_t stream) {
    const int*   ids  = (const int*)d_in[0];
    const int*   mask = (const int*)d_in[1];
    const float* W    = (const float*)d_in[2];
    float* out = (float*)d_out;

    char* ws = (char*)d_ws;
    __hip_bfloat16* Wb = (__hip_bfloat16*)ws;               // 46,080,000 B
    size_t off = (size_t)VOC * DMODEL * sizeof(__hip_bfloat16);
    int*   stoks_g = (int*)(ws + off);        off += (size_t)B_ROWS * SEQ * 4;  // 4 MB
    float* wts_g   = (float*)(ws + off);      off += (size_t)B_ROWS * SEQ * 4;  // 4 MB
    int*   n_g     = (int*)(ws + off);

    prep_trans<<<NBLK, 256, 0, stream>>>(W, Wb, ids, mask, stoks_g, wts_g, n_g);

    bm25_gather<<<B_ROWS, NT, 0, stream>>>(stoks_g, wts_g, n_g, Wb, out);
}